// Round 1
// baseline (581.765 us; speedup 1.0000x reference)
//
#include <hip/hip_runtime.h>
#include <math.h>

#define Hd 128
#define Dd 128
#define Rr 3
#define Ll 4
#define NB 16   // nodes per block in the GRU kernel (30000 % 16 == 0)

__device__ __forceinline__ int lower_bound_i32(const int* __restrict__ a, int n, int key) {
    int lo = 0, hi = n;
    while (lo < hi) {
        int mid = (lo + hi) >> 1;
        if (a[mid] < key) lo = mid + 1; else hi = mid;
    }
    return lo;
}

// Fold v-projection and out-projection into one matrix:
//   o[j] = sum_i h[i] * McT[i][j] + bc[j]
//   McT[i][j] = sum_k out_w[j][k] * wv[k][i],  wv[k] = in_proj_w[2H + k]
//   bc[j]    = sum_k out_w[j][k] * bv[k] + out_b[j]
__global__ void fold_proj_kernel(const float* __restrict__ in_proj_w,
                                 const float* __restrict__ in_proj_b,
                                 const float* __restrict__ out_w,
                                 const float* __restrict__ out_b,
                                 float* __restrict__ McT,
                                 float* __restrict__ bc)
{
    const int i = blockIdx.x;   // 0..127
    const int j = threadIdx.x;  // 0..127
    float acc = 0.f;
    for (int k = 0; k < Hd; ++k)
        acc = fmaf(out_w[j * Hd + k], in_proj_w[(2 * Hd + k) * Hd + i], acc);
    McT[i * Hd + j] = acc;
    if (i == 0) {
        float b = out_b[j];
        for (int k = 0; k < Hd; ++k)
            b = fmaf(out_w[j * Hd + k], in_proj_b[2 * Hd + k], b);
        bc[j] = b;
    }
}

__global__ __launch_bounds__(128) void gru_fused_kernel(
    const float* __restrict__ x_rank,
    const int* __restrict__ valid_idx, int nv,
    const float* __restrict__ r_whh, const float* __restrict__ r_wxh, const float* __restrict__ r_b,
    const float* __restrict__ u_whh, const float* __restrict__ u_wxh, const float* __restrict__ u_b,
    const float* __restrict__ c_whh, const float* __restrict__ c_wxh, const float* __restrict__ c_b,
    const float* __restrict__ McT, const float* __restrict__ bc,
    float* __restrict__ out, int N)
{
    __shared__ __align__(16) float h_s[NB][Hd];
    __shared__ __align__(16) float x_s[NB][Hd];
    __shared__ __align__(16) float rh_s[NB][Hd];
    __shared__ int lo_s[NB];
    __shared__ int hi_s[NB];

    const int j  = threadIdx.x;
    const int n0 = blockIdx.x * NB;

    const float rbj = r_b[j], ubj = u_b[j], cbj = c_b[j], bcj = bc[j];

    #pragma unroll
    for (int m = 0; m < NB; ++m) h_s[m][j] = 0.f;
    __syncthreads();

    for (int t = 0; t < Rr; ++t) {
        // ---- stage x_t and output-row ranges ----
        #pragma unroll
        for (int m = 0; m < NB; ++m) {
            const int n = n0 + m;
            x_s[m][j] = (n < N) ? x_rank[((size_t)n * Rr + t) * Dd + j] : 0.f;
        }
        if (j < NB) {
            const int n = n0 + j;
            if (n < N) {
                const int F = (n * Rr + t) * Ll;
                lo_s[j] = lower_bound_i32(valid_idx, nv, F);
                hi_s[j] = lower_bound_i32(valid_idx, nv, F + Ll);
            } else { lo_s[j] = 0; hi_s[j] = 0; }
        }
        __syncthreads();

        // ---- gates r and z (share h & x reads) ----
        float accr[NB], accz[NB];
        #pragma unroll
        for (int m = 0; m < NB; ++m) { accr[m] = rbj; accz[m] = ubj; }

        for (int i = 0; i < Hd; i += 4) {
            const float wr0 = r_whh[(i + 0) * Hd + j], wr1 = r_whh[(i + 1) * Hd + j],
                        wr2 = r_whh[(i + 2) * Hd + j], wr3 = r_whh[(i + 3) * Hd + j];
            const float wz0 = u_whh[(i + 0) * Hd + j], wz1 = u_whh[(i + 1) * Hd + j],
                        wz2 = u_whh[(i + 2) * Hd + j], wz3 = u_whh[(i + 3) * Hd + j];
            #pragma unroll
            for (int m = 0; m < NB; ++m) {
                const float4 hv = *(const float4*)(&h_s[m][i]);
                accr[m] = fmaf(hv.x, wr0, fmaf(hv.y, wr1, fmaf(hv.z, wr2, fmaf(hv.w, wr3, accr[m]))));
                accz[m] = fmaf(hv.x, wz0, fmaf(hv.y, wz1, fmaf(hv.z, wz2, fmaf(hv.w, wz3, accz[m]))));
            }
        }
        for (int i = 0; i < Hd; i += 4) {
            const float wr0 = r_wxh[(i + 0) * Hd + j], wr1 = r_wxh[(i + 1) * Hd + j],
                        wr2 = r_wxh[(i + 2) * Hd + j], wr3 = r_wxh[(i + 3) * Hd + j];
            const float wz0 = u_wxh[(i + 0) * Hd + j], wz1 = u_wxh[(i + 1) * Hd + j],
                        wz2 = u_wxh[(i + 2) * Hd + j], wz3 = u_wxh[(i + 3) * Hd + j];
            #pragma unroll
            for (int m = 0; m < NB; ++m) {
                const float4 xv = *(const float4*)(&x_s[m][i]);
                accr[m] = fmaf(xv.x, wr0, fmaf(xv.y, wr1, fmaf(xv.z, wr2, fmaf(xv.w, wr3, accr[m]))));
                accz[m] = fmaf(xv.x, wz0, fmaf(xv.y, wz1, fmaf(xv.z, wz2, fmaf(xv.w, wz3, accz[m]))));
            }
        }

        float zz[NB];
        #pragma unroll
        for (int m = 0; m < NB; ++m) {
            const float r = 1.f / (1.f + __expf(-accr[m]));
            zz[m] = 1.f / (1.f + __expf(-accz[m]));
            rh_s[m][j] = r * h_s[m][j];
        }
        __syncthreads();

        // ---- gate c: (r*h) @ c_whh + x @ c_wxh + c_b ----
        float accc[NB];
        #pragma unroll
        for (int m = 0; m < NB; ++m) accc[m] = cbj;

        for (int i = 0; i < Hd; i += 4) {
            const float wc0 = c_whh[(i + 0) * Hd + j], wc1 = c_whh[(i + 1) * Hd + j],
                        wc2 = c_whh[(i + 2) * Hd + j], wc3 = c_whh[(i + 3) * Hd + j];
            const float wx0 = c_wxh[(i + 0) * Hd + j], wx1 = c_wxh[(i + 1) * Hd + j],
                        wx2 = c_wxh[(i + 2) * Hd + j], wx3 = c_wxh[(i + 3) * Hd + j];
            #pragma unroll
            for (int m = 0; m < NB; ++m) {
                const float4 rv = *(const float4*)(&rh_s[m][i]);
                const float4 xv = *(const float4*)(&x_s[m][i]);
                accc[m] = fmaf(rv.x, wc0, fmaf(rv.y, wc1, fmaf(rv.z, wc2, fmaf(rv.w, wc3, accc[m]))));
                accc[m] = fmaf(xv.x, wx0, fmaf(xv.y, wx1, fmaf(xv.z, wx2, fmaf(xv.w, wx3, accc[m]))));
            }
        }

        // ---- h update: h' = h + z*(c - h) ----
        #pragma unroll
        for (int m = 0; m < NB; ++m) {
            const float c    = tanhf(accc[m]);
            const float hold = h_s[m][j];
            accc[m] = fmaf(zz[m], c - hold, hold);
        }
        __syncthreads();   // all r/z reads of old h are past B5 already; this orders vs o-loop below
        #pragma unroll
        for (int m = 0; m < NB; ++m) h_s[m][j] = accc[m];
        __syncthreads();

        // ---- fused output projection + scatter through valid_idx runs ----
        float acco[NB];
        #pragma unroll
        for (int m = 0; m < NB; ++m) acco[m] = bcj;

        for (int i = 0; i < Hd; i += 4) {
            const float wo0 = McT[(i + 0) * Hd + j], wo1 = McT[(i + 1) * Hd + j],
                        wo2 = McT[(i + 2) * Hd + j], wo3 = McT[(i + 3) * Hd + j];
            #pragma unroll
            for (int m = 0; m < NB; ++m) {
                const float4 hv = *(const float4*)(&h_s[m][i]);
                acco[m] = fmaf(hv.x, wo0, fmaf(hv.y, wo1, fmaf(hv.z, wo2, fmaf(hv.w, wo3, acco[m]))));
            }
        }

        #pragma unroll
        for (int m = 0; m < NB; ++m) {
            const float v = acco[m];
            for (int row = lo_s[m]; row < hi_s[m]; ++row)
                out[(size_t)row * Hd + j] = v;
        }
        __syncthreads();   // protect x_s/lo_s against next-iteration overwrite
    }
}

__global__ void he_order_kernel(const int* __restrict__ he_order,
                                float* __restrict__ out_tail, int nv)
{
    const int i = blockIdx.x * 256 + threadIdx.x;
    if (i < nv) out_tail[i] = (float)he_order[i];
}

extern "C" void kernel_launch(void* const* d_in, const int* in_sizes, int n_in,
                              void* d_out, int out_size, void* d_ws, size_t ws_size,
                              hipStream_t stream)
{
    const float* x_rank    = (const float*)d_in[0];
    // d_in[1] he_features, d_in[2] he_idx: dead (softmax over singleton axis == 1)
    const int*   valid_idx = (const int*)d_in[3];
    const int*   he_order  = (const int*)d_in[4];
    const float* r_whh = (const float*)d_in[5];
    const float* r_wxh = (const float*)d_in[6];
    const float* r_b   = (const float*)d_in[7];
    const float* u_whh = (const float*)d_in[8];
    const float* u_wxh = (const float*)d_in[9];
    const float* u_b   = (const float*)d_in[10];
    const float* c_whh = (const float*)d_in[11];
    const float* c_wxh = (const float*)d_in[12];
    const float* c_b   = (const float*)d_in[13];
    const float* in_proj_w = (const float*)d_in[14];
    const float* in_proj_b = (const float*)d_in[15];
    const float* out_w     = (const float*)d_in[16];
    const float* out_b     = (const float*)d_in[17];

    const int nv = in_sizes[3];
    const int N  = in_sizes[0] / (Rr * Dd);

    float* McT = (float*)d_ws;         // 128*128 floats
    float* bc  = McT + Hd * Hd;        // 128 floats

    float* out_f    = (float*)d_out;
    float* out_tail = out_f + (size_t)nv * Hd;

    fold_proj_kernel<<<Hd, Hd, 0, stream>>>(in_proj_w, in_proj_b, out_w, out_b, McT, bc);

    const int nblocks = (N + NB - 1) / NB;
    gru_fused_kernel<<<nblocks, 128, 0, stream>>>(
        x_rank, valid_idx, nv,
        r_whh, r_wxh, r_b, u_whh, u_wxh, u_b, c_whh, c_wxh, c_b,
        McT, bc, out_f, N);

    he_order_kernel<<<(nv + 255) / 256, 256, 0, stream>>>(he_order, out_tail, nv);
}